// Round 5
// baseline (274.277 us; speedup 1.0000x reference)
//
#include <hip/hip_runtime.h>
#include <hip/hip_bf16.h>
#include <stdint.h>

#define B_N 2
#define S_N 2048
#define D_N 1024
#define H_N 16

using bf8    = __attribute__((ext_vector_type(8))) short;   // 8 bf16 (4 VGPRs)
using f32x4  = __attribute__((ext_vector_type(4))) float;
using f32x16 = __attribute__((ext_vector_type(16))) float;

static __device__ __forceinline__ ushort f2b(float f) {
  uint32_t u = __builtin_bit_cast(uint32_t, f);
  u += 0x7fffu + ((u >> 16) & 1u);     // RNE
  return (ushort)(u >> 16);
}

static __device__ __forceinline__ uint32_t cvtpk(float a, float b) {
  uint32_t r;
  asm("v_cvt_pk_bf16_f32 %0, %1, %2" : "=v"(r) : "v"(a), "v"(b));
  return r;   // low = a, high = b
}

static __device__ __forceinline__ float h2f(ushort u) {
  return (float)__builtin_bit_cast(_Float16, u);
}

typedef __attribute__((address_space(1))) const uint32_t GU32;
typedef __attribute__((address_space(3))) uint32_t LU32;
static __device__ __forceinline__ void gload16(const void* g, void* l) {
  __builtin_amdgcn_global_load_lds((GU32*)g, (LU32*)l, 16, 0, 0);
}

// ---------------- f32 -> bf16 converts (fused) ----------------
__global__ __launch_bounds__(256) void cvt3_kernel(const float* __restrict__ a, const float* __restrict__ b,
                                                   const float* __restrict__ c, ushort* __restrict__ oa,
                                                   ushort* __restrict__ ob, ushort* __restrict__ oc) {
  const float* s; ushort* d;
  if (blockIdx.y == 0) { s = a; d = oa; }
  else if (blockIdx.y == 1) { s = b; d = ob; }
  else { s = c; d = oc; }
  int i = (blockIdx.x * 256 + threadIdx.x) * 4;
  float4 v = *(const float4*)(s + i);
  ushort4 o;
  o.x = f2b(v.x); o.y = f2b(v.y); o.z = f2b(v.z); o.w = f2b(v.w);
  *(ushort4*)(d + i) = o;
}

__global__ __launch_bounds__(256) void cvt4_kernel(const float* __restrict__ a, const float* __restrict__ b,
                                                   const float* __restrict__ c, const float* __restrict__ e,
                                                   ushort* __restrict__ oa, ushort* __restrict__ ob,
                                                   ushort* __restrict__ oc, ushort* __restrict__ oe) {
  const float* s; ushort* d;
  if (blockIdx.y == 0) { s = a; d = oa; }
  else if (blockIdx.y == 1) { s = b; d = ob; }
  else if (blockIdx.y == 2) { s = c; d = oc; }
  else { s = e; d = oe; }
  int i = (blockIdx.x * 256 + threadIdx.x) * 4;
  float4 v = *(const float4*)(s + i);
  ushort4 o;
  o.x = f2b(v.x); o.y = f2b(v.y); o.z = f2b(v.z); o.w = f2b(v.w);
  *(ushort4*)(d + i) = o;
}

// ---------------- structural-bias precompute ----------------
__global__ __launch_bounds__(256) void pack_codes_kernel(
    const int* __restrict__ f, const int* __restrict__ e, const int* __restrict__ ti,
    const int* __restrict__ tt, const int* __restrict__ ed, const int* __restrict__ ro,
    uint32_t* __restrict__ codes, int n) {
  int i = blockIdx.x * 256 + threadIdx.x;
  if (i >= n) return;
  uint32_t c = ((uint32_t)f[i] & 31u) | (((uint32_t)e[i] & 63u) << 5) |
               (((uint32_t)ti[i] & 127u) << 11) | (((uint32_t)tt[i] & 7u) << 18) |
               (((uint32_t)ro[i] & 7u) << 21) |
               ((ed[i] != 0) ? (1u << 24) : 0u) | ((f[i] == 0) ? (1u << 25) : 0u);
  codes[i] = c;
}

static __device__ __forceinline__ float bias_val(uint32_t a, uint32_t b) {
  uint32_t x = a ^ b;
  uint32_t o = a | b;
  float v = (o & 0x1000000u) ? 1.5f : 0.0f;   // has_edge
  v += (x & 0x1Fu)     ? 0.0f : 1.0f;          // field
  v += (x & 0x7E0u)    ? 0.0f : 1.0f;          // entity
  v += (x & 0x3F800u)  ? 0.0f : 0.5f;          // time
  v += (x & 0x1C0000u) ? 0.0f : 0.3f;          // token_type
  v += (x & 0xE00000u) ? 0.0f : 0.5f;          // role
  return (o & 0x2000000u) ? -30000.f : v;      // pad -> big negative
}

// BM[b][i][j] fp16 (symmetric), 8 elements per thread
__global__ __launch_bounds__(256) void bias_build(const uint32_t* __restrict__ codes,
                                                  ushort* __restrict__ BM) {
  int t = blockIdx.x * 256 + threadIdx.x;      // 0 .. B*S*S/8-1
  int j8 = (t & 255) * 8;                      // S/8 = 256
  int i  = (t >> 8) & 2047;
  int b  = t >> 19;                            // S*S/8 = 2^19
  uint32_t cq = codes[b * S_N + i];
  uint4 c0 = *(const uint4*)(codes + b * S_N + j8);
  uint4 c1 = *(const uint4*)(codes + b * S_N + j8 + 4);
  uint32_t cj[8] = {c0.x, c0.y, c0.z, c0.w, c1.x, c1.y, c1.z, c1.w};
  ushort o[8];
#pragma unroll
  for (int p = 0; p < 8; ++p) {
    _Float16 h = (_Float16)bias_val(cq, cj[p]);
    o[p] = __builtin_bit_cast(ushort, h);
  }
  *(uint4*)(BM + (size_t)t * 8) = *(const uint4*)o;
}

// ---------------- GEMM core: C[M,N] = A[M,K] @ W[N,K]^T + bias ----------------
template <int MODE>
static __device__ __forceinline__ void gemm_core(ushort* As, ushort* Bs,
    const ushort* __restrict__ A, const ushort* __restrict__ W, const float* __restrict__ bias,
    void* __restrict__ out, float scale) {
  const int tid = threadIdx.x, lane = tid & 63, wid = tid >> 6;
  const int g = lane >> 4, c = lane & 15;
  const int wm = wid >> 1, wn = wid & 1;
  const int m0 = blockIdx.y * 128, n0 = blockIdx.x * 128;

  f32x4 acc[4][4];
#pragma unroll
  for (int i = 0; i < 4; ++i)
#pragma unroll
    for (int j = 0; j < 4; ++j) acc[i][j] = (f32x4){0.f, 0.f, 0.f, 0.f};

  for (int k0 = 0; k0 < D_N; k0 += 32) {
#pragma unroll
    for (int j = 0; j < 2; ++j) {
      int idx = tid + j * 256;                  // 0..511
      int row = idx >> 2, c8 = (idx & 3) * 8;
      gload16(A + (size_t)(m0 + row) * D_N + k0 + c8, As + idx * 8);
      gload16(W + (size_t)(n0 + row) * D_N + k0 + c8, Bs + idx * 8);
    }
    __syncthreads();
    bf8 af[4], bw[4];
#pragma unroll
    for (int mi = 0; mi < 4; ++mi) af[mi] = *(const bf8*)(As + (wm * 64 + mi * 16 + c) * 32 + g * 8);
#pragma unroll
    for (int ni = 0; ni < 4; ++ni) bw[ni] = *(const bf8*)(Bs + (wn * 64 + ni * 16 + c) * 32 + g * 8);
#pragma unroll
    for (int mi = 0; mi < 4; ++mi)
#pragma unroll
      for (int ni = 0; ni < 4; ++ni)
        acc[mi][ni] = __builtin_amdgcn_mfma_f32_16x16x32_bf16(af[mi], bw[ni], acc[mi][ni], 0, 0, 0);
    __syncthreads();
  }

#pragma unroll
  for (int mi = 0; mi < 4; ++mi)
#pragma unroll
    for (int ni = 0; ni < 4; ++ni) {
      int ncol = n0 + wn * 64 + ni * 16 + c;
      float bv = bias[ncol];
      int hh = ncol >> 6, dd = ncol & 63;
      if (MODE == 2) {
        int mb = m0 + wm * 64 + mi * 16 + g * 4;
        int bb = mb >> 11, s = mb & 2047;
        ushort4 o4;
        o4.x = f2b((acc[mi][ni][0] + bv) * scale);
        o4.y = f2b((acc[mi][ni][1] + bv) * scale);
        o4.z = f2b((acc[mi][ni][2] + bv) * scale);
        o4.w = f2b((acc[mi][ni][3] + bv) * scale);
        *(ushort4*)((ushort*)out + (((size_t)bb * H_N + hh) * 64 + dd) * S_N + s) = o4;
      } else {
#pragma unroll
        for (int r = 0; r < 4; ++r) {
          int m = m0 + wm * 64 + mi * 16 + g * 4 + r;
          float v = (acc[mi][ni][r] + bv) * scale;
          if (MODE == 0) {
            int bb = m >> 11, s = m & 2047;
            ((ushort*)out)[(((size_t)bb * H_N + hh) * S_N + s) * 64 + dd] = f2b(v);
          } else {
            ((float*)out)[(size_t)m * D_N + ncol] = v;
          }
        }
      }
    }
}

__global__ __launch_bounds__(256) void gemm_qkv(
    const ushort* __restrict__ Xq, const ushort* __restrict__ Xk, const ushort* __restrict__ Xv,
    const ushort* __restrict__ Wq, const ushort* __restrict__ Wk, const ushort* __restrict__ Wv,
    const float* __restrict__ bq, const float* __restrict__ bk, const float* __restrict__ bv,
    ushort* __restrict__ Qo, ushort* __restrict__ Ko, ushort* __restrict__ Vo) {
  __shared__ __align__(16) ushort As[128 * 32];
  __shared__ __align__(16) ushort Bs[128 * 32];
  if (blockIdx.z == 0)      gemm_core<0>(As, Bs, Xq, Wq, bq, Qo, 0.125f);
  else if (blockIdx.z == 1) gemm_core<0>(As, Bs, Xk, Wk, bk, Ko, 1.0f);
  else                      gemm_core<2>(As, Bs, Xv, Wv, bv, Vo, 1.0f);
}

__global__ __launch_bounds__(256) void gemm_o(const ushort* __restrict__ A, const ushort* __restrict__ W,
                                              const float* __restrict__ bias, float* __restrict__ out) {
  __shared__ __align__(16) ushort As[128 * 32];
  __shared__ __align__(16) ushort Bs[128 * 32];
  gemm_core<1>(As, Bs, A, W, bias, out, 1.0f);
}

// ---------------- flash attention: split-KV x2, 4-warp 32x32 swapped-QK^T ----------
// grid (S/128, B*H, 2), 256 thr (4 warps x 32 q rows), each block does half the KV range.
// Swapped QK^T: S^T = mfma(K, Q) -> score col q = lane&31 (lane-local softmax).
// Partial O (f32, unnormalized), m, l written to ws; combine_kernel merges halves.
__global__ __launch_bounds__(256, 4) void attn_kernel(const ushort* __restrict__ Qw, const ushort* __restrict__ Kw,
                                                      const ushort* __restrict__ VT, const ushort* __restrict__ BMh,
                                                      float* __restrict__ Op, float* __restrict__ Mp,
                                                      float* __restrict__ Lp) {
  __shared__ __align__(16) ushort Ks[2][64 * 64];
  __shared__ __align__(16) ushort Vs[2][64 * 64];   // V^T tile: [d][kv]
  const int tid = threadIdx.x, lane = tid & 63, w = tid >> 6;
  const int l31 = lane & 31, hi = lane >> 5;
  const int bh = blockIdx.y, b = bh >> 4;
  const int q0 = blockIdx.x * 128;
  const int qg = q0 + w * 32 + l31;                 // this lane's q row
  const int kvh = blockIdx.z;                       // KV half
  const int kvbase = kvh * (S_N / 2);               // 1024 kv per half, 16 tiles

  // Q fragments (B-operand): d = ks*16 + hi*8 + j
  bf8 aq[4];
  {
    const ushort* qp = Qw + ((size_t)bh * S_N + qg) * 64;
#pragma unroll
    for (int ks = 0; ks < 4; ++ks) aq[ks] = *(const bf8*)(qp + ks * 16 + hi * 8);
  }
  const ushort* Brow  = BMh + ((size_t)b * S_N + qg) * S_N + kvbase;  // fp16 bias row
  const ushort* Kbase = Kw + (size_t)bh * (S_N * 64) + (size_t)kvbase * 64;
  const ushort* Vbase = VT + (size_t)bh * (64 * S_N) + kvbase;

  float mr = -1e30f, lr = 0.f;
  f32x16 o0, o1;
#pragma unroll
  for (int r = 0; r < 16; ++r) { o0[r] = 0.f; o1[r] = 0.f; }

  const int CROW0[16] = {0,1,2,3, 8,9,10,11, 16,17,18,19, 24,25,26,27};

  auto STAGE = [&](int bi, int kv0) {               // 4 gload16 / thread
#pragma unroll
    for (int j = 0; j < 2; ++j) {
      int idx = tid + j * 256;
      int row = idx >> 3, sl = ((idx & 7) ^ (row & 7)) * 8;
      gload16(Kbase + (size_t)(kv0 + row) * 64 + sl, &Ks[bi][idx * 8]);
      gload16(Vbase + (size_t)row * S_N + kv0 + sl, &Vs[bi][idx * 8]);
    }
  };
  auto BLOAD = [&](ushort4* braw, int kv0) {        // 8 x 8B loads, raw (no cvt -> no wait)
#pragma unroll
    for (int t = 0; t < 2; ++t)
#pragma unroll
      for (int g = 0; g < 4; ++g)
        braw[t * 4 + g] = *(const ushort4*)(Brow + kv0 + t * 32 + g * 8 + 4 * hi);
  };

  auto TILE = [&](int bi, const ushort4* braw) {
    // scores init = bias (s[t][r=g*4+j] covers kv = t*32 + g*8 + 4*hi + j)
    f32x16 s0, s1;
#pragma unroll
    for (int g = 0; g < 4; ++g) {
      ushort4 u0 = braw[g], u1 = braw[4 + g];
      s0[g * 4 + 0] = h2f(u0.x); s0[g * 4 + 1] = h2f(u0.y);
      s0[g * 4 + 2] = h2f(u0.z); s0[g * 4 + 3] = h2f(u0.w);
      s1[g * 4 + 0] = h2f(u1.x); s1[g * 4 + 1] = h2f(u1.y);
      s1[g * 4 + 2] = h2f(u1.z); s1[g * 4 + 3] = h2f(u1.w);
    }
    // QK^T (swapped): A = K rows, B = Q
    const ushort* Kb = &Ks[bi][0];
    __builtin_amdgcn_s_setprio(1);
#pragma unroll
    for (int ks = 0; ks < 4; ++ks) {
      int sl0 = ((ks * 2 + hi) ^ (l31 & 7)) * 8;
      bf8 k0 = *(const bf8*)(Kb + l31 * 64 + sl0);
      bf8 k1 = *(const bf8*)(Kb + (32 + l31) * 64 + sl0);
      s0 = __builtin_amdgcn_mfma_f32_32x32x16_bf16(k0, aq[ks], s0, 0, 0, 0);
      s1 = __builtin_amdgcn_mfma_f32_32x32x16_bf16(k1, aq[ks], s1, 0, 0, 0);
    }
    __builtin_amdgcn_s_setprio(0);

    // row max: pairwise tree (depth ~5)
    float m8[8];
#pragma unroll
    for (int r = 0; r < 8; ++r)
      m8[r] = fmaxf(fmaxf(s0[r], s0[r + 8]), fmaxf(s1[r], s1[r + 8]));
    float m4a = fmaxf(m8[0], m8[4]), m4b = fmaxf(m8[1], m8[5]);
    float m4c = fmaxf(m8[2], m8[6]), m4d = fmaxf(m8[3], m8[7]);
    float mt = fmaxf(fmaxf(m4a, m4b), fmaxf(m4c, m4d));
    mt = fmaxf(mt, __shfl_xor(mt, 32));

    if (__any(mt > mr + 8.0f)) {          // defer-max (T13): rescale only when needed
      float mn = fmaxf(mr, mt);
      float sc = __expf(mr - mn);
      lr *= sc;
#pragma unroll
      for (int r = 0; r < 16; ++r) {
        float scr = __shfl(sc, CROW0[r] + 4 * hi);
        o0[r] *= scr; o1[r] *= scr;
      }
      mr = mn;
    }
#pragma unroll
    for (int r = 0; r < 16; ++r) { s0[r] = __expf(s0[r] - mr); s1[r] = __expf(s1[r] - mr); }
    // row sum: pairwise tree
    float a8[8];
#pragma unroll
    for (int r = 0; r < 8; ++r)
      a8[r] = (s0[r] + s0[r + 8]) + (s1[r] + s1[r + 8]);
    float a4a = a8[0] + a8[4], a4b = a8[1] + a8[5], a4c = a8[2] + a8[6], a4d = a8[3] + a8[7];
    float sum = (a4a + a4b) + (a4c + a4d);
    sum += __shfl_xor(sum, 32);
    lr += sum;

    // P (f32, S^T layout) -> PV A-fragments via cvt_pk + partner exchange
    bf8 pa[4];
#pragma unroll
    for (int t = 0; t < 2; ++t) {
      uint32_t wv[4][2];
#pragma unroll
      for (int g = 0; g < 4; ++g) {
        const float* sp = (t == 0) ? (const float*)&s0 : (const float*)&s1;
        wv[g][0] = cvtpk(sp[g * 4 + 0], sp[g * 4 + 1]);
        wv[g][1] = cvtpk(sp[g * 4 + 2], sp[g * 4 + 3]);
      }
#pragma unroll
      for (int pr = 0; pr < 2; ++pr) {
        uint32_t x0 = hi ? wv[2 * pr][0] : wv[2 * pr + 1][0];
        uint32_t x1 = hi ? wv[2 * pr][1] : wv[2 * pr + 1][1];
        uint32_t r0 = (uint32_t)__shfl_xor((int)x0, 32);
        uint32_t r1 = (uint32_t)__shfl_xor((int)x1, 32);
        uint4 pw;
        pw.x = hi ? r0 : wv[2 * pr][0];
        pw.y = hi ? r1 : wv[2 * pr][1];
        pw.z = hi ? wv[2 * pr + 1][0] : r0;
        pw.w = hi ? wv[2 * pr + 1][1] : r1;
        pa[t * 2 + pr] = __builtin_bit_cast(bf8, pw);
      }
    }

    // PV: O[q][d] += P[q][kv] V[kv][d]; V^T tile rows = d
    const ushort* Vb = &Vs[bi][0];
    __builtin_amdgcn_s_setprio(1);
#pragma unroll
    for (int ks = 0; ks < 4; ++ks) {
      int sl0 = ((ks * 2 + hi) ^ (l31 & 7)) * 8;
      bf8 v0 = *(const bf8*)(Vb + l31 * 64 + sl0);
      bf8 v1 = *(const bf8*)(Vb + (32 + l31) * 64 + sl0);
      o0 = __builtin_amdgcn_mfma_f32_32x32x16_bf16(pa[ks], v0, o0, 0, 0, 0);
      o1 = __builtin_amdgcn_mfma_f32_32x32x16_bf16(pa[ks], v1, o1, 0, 0, 0);
    }
    __builtin_amdgcn_s_setprio(0);
  };

  ushort4 biasA[8], biasB[8];
  STAGE(0, 0);  BLOAD(biasA, 0);
  STAGE(1, 64); BLOAD(biasB, 64);

#pragma unroll 1
  for (int t = 0; t < 16; t += 2) {
    asm volatile("s_waitcnt vmcnt(12)" ::: "memory");   // stage(t)+bias(t) drained
    __builtin_amdgcn_s_barrier();
    __builtin_amdgcn_sched_barrier(0);
    TILE(0, biasA);
    __builtin_amdgcn_s_barrier();                       // all warps done reading buf0
    __builtin_amdgcn_sched_barrier(0);
    if (t + 2 < 16) { STAGE(0, (t + 2) * 64); BLOAD(biasA, (t + 2) * 64); }

    if (t + 2 < 16) asm volatile("s_waitcnt vmcnt(12)" ::: "memory");
    else            asm volatile("s_waitcnt vmcnt(0)" ::: "memory");
    __builtin_amdgcn_s_barrier();
    __builtin_amdgcn_sched_barrier(0);
    TILE(1, biasB);
    __builtin_amdgcn_s_barrier();
    __builtin_amdgcn_sched_barrier(0);
    if (t + 3 < 16) { STAGE(1, (t + 3) * 64); BLOAD(biasB, (t + 3) * 64); }
  }

  // epilogue: write partial m, l, O (unnormalized, f32)
  if (hi == 0) {
    size_t mi = ((size_t)kvh * 32 + bh) * S_N + qg;
    Mp[mi] = mr;
    Lp[mi] = lr;
  }
#pragma unroll
  for (int r = 0; r < 16; ++r) {
    int q = q0 + w * 32 + CROW0[r] + 4 * hi;
    size_t base = (((size_t)kvh * 32 + bh) * S_N + q) * 64 + l31;
    Op[base]      = o0[r];
    Op[base + 32] = o1[r];
  }
}

// merge the two KV halves: out = (O0*e^{m0-M} + O1*e^{m1-M}) / (l0*e^{m0-M} + l1*e^{m1-M})
__global__ __launch_bounds__(256) void combine_kernel(const float* __restrict__ Op,
                                                      const float* __restrict__ Mp,
                                                      const float* __restrict__ Lp,
                                                      ushort* __restrict__ AO) {
  int idx = blockIdx.x * 256 + threadIdx.x;   // B*H*S*8 = 524288
  int d0 = (idx & 7) * 8;
  int q  = (idx >> 3) & 2047;
  int bh = idx >> 14;
  size_t r0 = (size_t)bh * S_N + q;
  size_t r1 = (size_t)(32 + bh) * S_N + q;
  float m0 = Mp[r0], m1 = Mp[r1], l0 = Lp[r0], l1 = Lp[r1];
  float M = fmaxf(m0, m1);
  float w0 = __expf(m0 - M), w1 = __expf(m1 - M);
  float invL = 1.0f / (l0 * w0 + l1 * w1);
  float4 a0 = *(const float4*)(Op + r0 * 64 + d0);
  float4 a1 = *(const float4*)(Op + r0 * 64 + d0 + 4);
  float4 b0 = *(const float4*)(Op + r1 * 64 + d0);
  float4 b1 = *(const float4*)(Op + r1 * 64 + d0 + 4);
  int b = bh >> 4, h = bh & 15;
  ushort o[8];
  o[0] = f2b((a0.x * w0 + b0.x * w1) * invL);
  o[1] = f2b((a0.y * w0 + b0.y * w1) * invL);
  o[2] = f2b((a0.z * w0 + b0.z * w1) * invL);
  o[3] = f2b((a0.w * w0 + b0.w * w1) * invL);
  o[4] = f2b((a1.x * w0 + b1.x * w1) * invL);
  o[5] = f2b((a1.y * w0 + b1.y * w1) * invL);
  o[6] = f2b((a1.z * w0 + b1.z * w1) * invL);
  o[7] = f2b((a1.w * w0 + b1.w * w1) * invL);
  *(uint4*)(AO + ((size_t)b * S_N + q) * D_N + h * 64 + d0) = *(const uint4*)o;
}

extern "C" void kernel_launch(void* const* d_in, const int* in_sizes, int n_in,
                              void* d_out, int out_size, void* d_ws, size_t ws_size,
                              hipStream_t stream) {
  (void)in_sizes; (void)n_in; (void)out_size; (void)ws_size;
  const float* query = (const float*)d_in[0];
  const float* key_  = (const float*)d_in[1];
  const float* value = (const float*)d_in[2];
  const int* fid  = (const int*)d_in[3];
  const int* eid  = (const int*)d_in[4];
  const int* tmid = (const int*)d_in[5];
  const int* ttid = (const int*)d_in[6];
  const int* edid = (const int*)d_in[7];
  const int* rlid = (const int*)d_in[8];
  const float* Wq = (const float*)d_in[9];  const float* bq = (const float*)d_in[10];
  const float* Wk = (const float*)d_in[11]; const float* bk = (const float*)d_in[12];
  const float* Wv = (const float*)d_in[13]; const float* bv = (const float*)d_in[14];
  const float* Wo = (const float*)d_in[15]; const float* bo = (const float*)d_in[16];

  char* ws = (char*)d_ws;
  const size_t MB = 1024 * 1024;
  // Projection phase: Xq 0-8, Xk 8-16, Xv 16-24, Wqb 24-26, Wkb 26-28, Wvb 28-30 (MB).
  // After gemm_qkv those are dead; BM fp16 (16.8MB) overwrites [0,17).
  ushort* Xq  = (ushort*)(ws);
  ushort* Xk  = (ushort*)(ws + 8 * MB);
  ushort* Xv  = (ushort*)(ws + 16 * MB);
  ushort* Wqb = (ushort*)(ws + 24 * MB);
  ushort* Wkb = (ushort*)(ws + 26 * MB);
  ushort* Wvb = (ushort*)(ws + 28 * MB);
  ushort* BMh = (ushort*)(ws);                      // fp16 bias [B,S,S]
  ushort* Qws = (ushort*)(ws + 30 * MB);
  ushort* Kws = (ushort*)(ws + 38 * MB);
  ushort* VTw = (ushort*)(ws + 46 * MB);
  ushort* AOw = (ushort*)(ws + 54 * MB);
  ushort* Wob = (ushort*)(ws + 62 * MB);
  uint32_t* codes = (uint32_t*)(ws + 64 * MB);
  float* Op = (float*)(ws + 65 * MB);               // 2x[B*H][S][64] f32 = 33.6MB
  float* Mp = (float*)(ws + 99 * MB);               // 2x[B*H][S] f32 = 0.5MB
  float* Lp = (float*)(ws + 99 * MB + 512 * 1024);
  // total ws use: ~100MB

  const int MK = B_N * S_N * D_N;
  const int WK = D_N * D_N;
  cvt3_kernel<<<dim3(MK / 1024, 3), 256, 0, stream>>>(query, key_, value, Xq, Xk, Xv);
  cvt4_kernel<<<dim3(WK / 1024, 4), 256, 0, stream>>>(Wq, Wk, Wv, Wo, Wqb, Wkb, Wvb, Wob);
  pack_codes_kernel<<<(B_N * S_N) / 256, 256, 0, stream>>>(fid, eid, tmid, ttid, edid, rlid, codes, B_N * S_N);

  gemm_qkv<<<dim3(D_N / 128, (B_N * S_N) / 128, 3), 256, 0, stream>>>(
      Xq, Xk, Xv, Wqb, Wkb, Wvb, bq, bk, bv, Qws, Kws, VTw);
  // bias matrix overwrites Xq/Xk/start-of-Xv region (dead after gemm_qkv)
  bias_build<<<(B_N * S_N * S_N / 8) / 256, 256, 0, stream>>>(codes, BMh);
  attn_kernel<<<dim3(S_N / 128, B_N * H_N, 2), 256, 0, stream>>>(Qws, Kws, VTw, BMh, Op, Mp, Lp);
  combine_kernel<<<(B_N * H_N * S_N * 8) / 256, 256, 0, stream>>>(Op, Mp, Lp, AOw);
  gemm_o<<<dim3(D_N / 128, (B_N * S_N) / 128), 256, 0, stream>>>(AOw, Wob, bo, (float*)d_out);
}

// Round 7
// 194.352 us; speedup vs baseline: 1.4112x; 1.4112x over previous
//
#include <hip/hip_runtime.h>
#include <hip/hip_bf16.h>
#include <stdint.h>

#define B_N 2
#define S_N 2048
#define D_N 1024
#define H_N 16
#define LOG2E 1.44269504f

using bf8    = __attribute__((ext_vector_type(8))) short;   // 8 bf16 (4 VGPRs)
using f32x4  = __attribute__((ext_vector_type(4))) float;
using f32x16 = __attribute__((ext_vector_type(16))) float;

static __device__ __forceinline__ ushort f2b(float f) {
  uint32_t u = __builtin_bit_cast(uint32_t, f);
  u += 0x7fffu + ((u >> 16) & 1u);     // RNE
  return (ushort)(u >> 16);
}

static __device__ __forceinline__ uint32_t cvtpk(float a, float b) {
  uint32_t r;
  asm("v_cvt_pk_bf16_f32 %0, %1, %2" : "=v"(r) : "v"(a), "v"(b));
  return r;   // low = a, high = b
}

static __device__ __forceinline__ float h2f(ushort u) {
  return (float)__builtin_bit_cast(_Float16, u);
}

typedef __attribute__((address_space(1))) const uint32_t GU32;
typedef __attribute__((address_space(3))) uint32_t LU32;
static __device__ __forceinline__ void gload16(const void* g, void* l) {
  __builtin_amdgcn_global_load_lds((GU32*)g, (LU32*)l, 16, 0, 0);
}

// ---------------- f32 -> bf16 converts (fused) ----------------
__global__ __launch_bounds__(256) void cvt3_kernel(const float* __restrict__ a, const float* __restrict__ b,
                                                   const float* __restrict__ c, ushort* __restrict__ oa,
                                                   ushort* __restrict__ ob, ushort* __restrict__ oc) {
  const float* s; ushort* d;
  if (blockIdx.y == 0) { s = a; d = oa; }
  else if (blockIdx.y == 1) { s = b; d = ob; }
  else { s = c; d = oc; }
  int i = (blockIdx.x * 256 + threadIdx.x) * 4;
  float4 v = *(const float4*)(s + i);
  ushort4 o;
  o.x = f2b(v.x); o.y = f2b(v.y); o.z = f2b(v.z); o.w = f2b(v.w);
  *(ushort4*)(d + i) = o;
}

__global__ __launch_bounds__(256) void cvt4_kernel(const float* __restrict__ a, const float* __restrict__ b,
                                                   const float* __restrict__ c, const float* __restrict__ e,
                                                   ushort* __restrict__ oa, ushort* __restrict__ ob,
                                                   ushort* __restrict__ oc, ushort* __restrict__ oe) {
  const float* s; ushort* d;
  if (blockIdx.y == 0) { s = a; d = oa; }
  else if (blockIdx.y == 1) { s = b; d = ob; }
  else if (blockIdx.y == 2) { s = c; d = oc; }
  else { s = e; d = oe; }
  int i = (blockIdx.x * 256 + threadIdx.x) * 4;
  float4 v = *(const float4*)(s + i);
  ushort4 o;
  o.x = f2b(v.x); o.y = f2b(v.y); o.z = f2b(v.z); o.w = f2b(v.w);
  *(ushort4*)(d + i) = o;
}

// ---------------- structural-bias precompute ----------------
__global__ __launch_bounds__(256) void pack_codes_kernel(
    const int* __restrict__ f, const int* __restrict__ e, const int* __restrict__ ti,
    const int* __restrict__ tt, const int* __restrict__ ed, const int* __restrict__ ro,
    uint32_t* __restrict__ codes, int n) {
  int i = blockIdx.x * 256 + threadIdx.x;
  if (i >= n) return;
  uint32_t c = ((uint32_t)f[i] & 31u) | (((uint32_t)e[i] & 63u) << 5) |
               (((uint32_t)ti[i] & 127u) << 11) | (((uint32_t)tt[i] & 7u) << 18) |
               (((uint32_t)ro[i] & 7u) << 21) |
               ((ed[i] != 0) ? (1u << 24) : 0u) | ((f[i] == 0) ? (1u << 25) : 0u);
  codes[i] = c;
}

static __device__ __forceinline__ float bias_val(uint32_t a, uint32_t b) {
  uint32_t x = a ^ b;
  uint32_t o = a | b;
  float v = (o & 0x1000000u) ? 1.5f : 0.0f;   // has_edge
  v += (x & 0x1Fu)     ? 0.0f : 1.0f;          // field
  v += (x & 0x7E0u)    ? 0.0f : 1.0f;          // entity
  v += (x & 0x3F800u)  ? 0.0f : 0.5f;          // time
  v += (x & 0x1C0000u) ? 0.0f : 0.3f;          // token_type
  v += (x & 0xE00000u) ? 0.0f : 0.5f;          // role
  return (o & 0x2000000u) ? -30000.f : v;      // pad -> big negative
}

// BM[b][i][j] fp16 (symmetric), pre-scaled by log2(e) for exp2-domain softmax
__global__ __launch_bounds__(256) void bias_build(const uint32_t* __restrict__ codes,
                                                  ushort* __restrict__ BM) {
  int t = blockIdx.x * 256 + threadIdx.x;      // 0 .. B*S*S/8-1
  int j8 = (t & 255) * 8;                      // S/8 = 256
  int i  = (t >> 8) & 2047;
  int b  = t >> 19;                            // S*S/8 = 2^19
  uint32_t cq = codes[b * S_N + i];
  uint4 c0 = *(const uint4*)(codes + b * S_N + j8);
  uint4 c1 = *(const uint4*)(codes + b * S_N + j8 + 4);
  uint32_t cj[8] = {c0.x, c0.y, c0.z, c0.w, c1.x, c1.y, c1.z, c1.w};
  ushort o[8];
#pragma unroll
  for (int p = 0; p < 8; ++p) {
    _Float16 h = (_Float16)(bias_val(cq, cj[p]) * LOG2E);
    o[p] = __builtin_bit_cast(ushort, h);
  }
  *(uint4*)(BM + (size_t)t * 8) = *(const uint4*)o;
}

// ---------------- GEMM core: C[M,N] = A[M,K] @ W[N,K]^T + bias ----------------
template <int MODE>
static __device__ __forceinline__ void gemm_core(ushort* As, ushort* Bs,
    const ushort* __restrict__ A, const ushort* __restrict__ W, const float* __restrict__ bias,
    void* __restrict__ out, float scale) {
  const int tid = threadIdx.x, lane = tid & 63, wid = tid >> 6;
  const int g = lane >> 4, c = lane & 15;
  const int wm = wid >> 1, wn = wid & 1;
  const int m0 = blockIdx.y * 128, n0 = blockIdx.x * 128;

  f32x4 acc[4][4];
#pragma unroll
  for (int i = 0; i < 4; ++i)
#pragma unroll
    for (int j = 0; j < 4; ++j) acc[i][j] = (f32x4){0.f, 0.f, 0.f, 0.f};

  for (int k0 = 0; k0 < D_N; k0 += 32) {
#pragma unroll
    for (int j = 0; j < 2; ++j) {
      int idx = tid + j * 256;                  // 0..511
      int row = idx >> 2, c8 = (idx & 3) * 8;
      gload16(A + (size_t)(m0 + row) * D_N + k0 + c8, As + idx * 8);
      gload16(W + (size_t)(n0 + row) * D_N + k0 + c8, Bs + idx * 8);
    }
    __syncthreads();
    bf8 af[4], bw[4];
#pragma unroll
    for (int mi = 0; mi < 4; ++mi) af[mi] = *(const bf8*)(As + (wm * 64 + mi * 16 + c) * 32 + g * 8);
#pragma unroll
    for (int ni = 0; ni < 4; ++ni) bw[ni] = *(const bf8*)(Bs + (wn * 64 + ni * 16 + c) * 32 + g * 8);
#pragma unroll
    for (int mi = 0; mi < 4; ++mi)
#pragma unroll
      for (int ni = 0; ni < 4; ++ni)
        acc[mi][ni] = __builtin_amdgcn_mfma_f32_16x16x32_bf16(af[mi], bw[ni], acc[mi][ni], 0, 0, 0);
    __syncthreads();
  }

#pragma unroll
  for (int mi = 0; mi < 4; ++mi)
#pragma unroll
    for (int ni = 0; ni < 4; ++ni) {
      int ncol = n0 + wn * 64 + ni * 16 + c;
      float bv = bias[ncol];
      int hh = ncol >> 6, dd = ncol & 63;
      if (MODE == 2) {
        int mb = m0 + wm * 64 + mi * 16 + g * 4;
        int bb = mb >> 11, s = mb & 2047;
        ushort4 o4;
        o4.x = f2b((acc[mi][ni][0] + bv) * scale);
        o4.y = f2b((acc[mi][ni][1] + bv) * scale);
        o4.z = f2b((acc[mi][ni][2] + bv) * scale);
        o4.w = f2b((acc[mi][ni][3] + bv) * scale);
        *(ushort4*)((ushort*)out + (((size_t)bb * H_N + hh) * 64 + dd) * S_N + s) = o4;
      } else {
#pragma unroll
        for (int r = 0; r < 4; ++r) {
          int m = m0 + wm * 64 + mi * 16 + g * 4 + r;
          float v = (acc[mi][ni][r] + bv) * scale;
          if (MODE == 0) {
            int bb = m >> 11, s = m & 2047;
            ((ushort*)out)[(((size_t)bb * H_N + hh) * S_N + s) * 64 + dd] = f2b(v);
          } else {
            ((float*)out)[(size_t)m * D_N + ncol] = v;
          }
        }
      }
    }
}

__global__ __launch_bounds__(256) void gemm_qkv(
    const ushort* __restrict__ Xq, const ushort* __restrict__ Xk, const ushort* __restrict__ Xv,
    const ushort* __restrict__ Wq, const ushort* __restrict__ Wk, const ushort* __restrict__ Wv,
    const float* __restrict__ bq, const float* __restrict__ bk, const float* __restrict__ bv,
    ushort* __restrict__ Qo, ushort* __restrict__ Ko, ushort* __restrict__ Vo) {
  __shared__ __align__(16) ushort As[128 * 32];
  __shared__ __align__(16) ushort Bs[128 * 32];
  // Q carries 1/sqrt(64) * log2(e) so softmax runs in exp2 domain
  if (blockIdx.z == 0)      gemm_core<0>(As, Bs, Xq, Wq, bq, Qo, 0.125f * LOG2E);
  else if (blockIdx.z == 1) gemm_core<0>(As, Bs, Xk, Wk, bk, Ko, 1.0f);
  else                      gemm_core<2>(As, Bs, Xv, Wv, bv, Vo, 1.0f);
}

__global__ __launch_bounds__(256) void gemm_o(const ushort* __restrict__ A, const ushort* __restrict__ W,
                                              const float* __restrict__ bias, float* __restrict__ out) {
  __shared__ __align__(16) ushort As[128 * 32];
  __shared__ __align__(16) ushort Bs[128 * 32];
  gemm_core<1>(As, Bs, A, W, bias, out, 1.0f);
}

// ---------------- flash attention: single-pass, 2-warp blocks, 32x32 swapped-QK^T ---
// grid (S/64, B*H), 128 thr (2 warps x 32 q rows), full KV sweep per block.
// 1024 blocks = 4 independent blocks/CU -> cross-block latency overlap.
// Scores arrive in log2 domain (Q and bias pre-scaled); softmax uses exp2.
__global__ __launch_bounds__(128, 2) void attn_kernel(const ushort* __restrict__ Qw, const ushort* __restrict__ Kw,
                                                      const ushort* __restrict__ VT, const ushort* __restrict__ BMh,
                                                      ushort* __restrict__ AO) {
  __shared__ __align__(16) ushort Ks[2][64 * 64];
  __shared__ __align__(16) ushort Vs[2][64 * 64];   // V^T tile: [d][kv]
  const int tid = threadIdx.x, lane = tid & 63, w = tid >> 6;  // w in 0..1
  const int l31 = lane & 31, hi = lane >> 5;
  const int bh = blockIdx.y, b = bh >> 4, h = bh & 15;
  const int q0 = blockIdx.x * 64;
  const int qg = q0 + w * 32 + l31;                 // this lane's q row

  // Q fragments (B-operand): d = ks*16 + hi*8 + j
  bf8 aq[4];
  {
    const ushort* qp = Qw + ((size_t)bh * S_N + qg) * 64;
#pragma unroll
    for (int ks = 0; ks < 4; ++ks) aq[ks] = *(const bf8*)(qp + ks * 16 + hi * 8);
  }
  const ushort* Brow  = BMh + ((size_t)b * S_N + qg) * S_N;   // fp16 bias row (symmetric)
  const ushort* Kbase = Kw + (size_t)bh * (S_N * 64);
  const ushort* Vbase = VT + (size_t)bh * (64 * S_N);

  float mr = -1e30f, lr = 0.f;
  f32x16 o0, o1;
#pragma unroll
  for (int r = 0; r < 16; ++r) { o0[r] = 0.f; o1[r] = 0.f; }

  const int CROW0[16] = {0,1,2,3, 8,9,10,11, 16,17,18,19, 24,25,26,27};

  auto STAGE = [&](int bi, int kv0) {               // 8 gload16 / thread
#pragma unroll
    for (int j = 0; j < 4; ++j) {
      int idx = tid + j * 128;                      // 0..511
      int row = idx >> 3, sl = ((idx & 7) ^ (row & 7)) * 8;
      gload16(Kbase + (size_t)(kv0 + row) * 64 + sl, &Ks[bi][idx * 8]);
      gload16(Vbase + (size_t)row * S_N + kv0 + sl, &Vs[bi][idx * 8]);
    }
  };
  auto BLOAD = [&](ushort4* braw, int kv0) {        // 8 x 8B loads, raw (no cvt -> no wait)
#pragma unroll
    for (int t = 0; t < 2; ++t)
#pragma unroll
      for (int g = 0; g < 4; ++g)
        braw[t * 4 + g] = *(const ushort4*)(Brow + kv0 + t * 32 + g * 8 + 4 * hi);
  };

  auto TILE = [&](int bi, const ushort4* braw) {
    // scores init = bias (s[t][r=g*4+j] covers kv = t*32 + g*8 + 4*hi + j)
    f32x16 s0, s1;
#pragma unroll
    for (int g = 0; g < 4; ++g) {
      ushort4 u0 = braw[g], u1 = braw[4 + g];
      s0[g * 4 + 0] = h2f(u0.x); s0[g * 4 + 1] = h2f(u0.y);
      s0[g * 4 + 2] = h2f(u0.z); s0[g * 4 + 3] = h2f(u0.w);
      s1[g * 4 + 0] = h2f(u1.x); s1[g * 4 + 1] = h2f(u1.y);
      s1[g * 4 + 2] = h2f(u1.z); s1[g * 4 + 3] = h2f(u1.w);
    }
    // QK^T (swapped): A = K rows, B = Q
    const ushort* Kb = &Ks[bi][0];
    __builtin_amdgcn_s_setprio(1);
#pragma unroll
    for (int ks = 0; ks < 4; ++ks) {
      int sl0 = ((ks * 2 + hi) ^ (l31 & 7)) * 8;
      bf8 k0 = *(const bf8*)(Kb + l31 * 64 + sl0);
      bf8 k1 = *(const bf8*)(Kb + (32 + l31) * 64 + sl0);
      s0 = __builtin_amdgcn_mfma_f32_32x32x16_bf16(k0, aq[ks], s0, 0, 0, 0);
      s1 = __builtin_amdgcn_mfma_f32_32x32x16_bf16(k1, aq[ks], s1, 0, 0, 0);
    }
    __builtin_amdgcn_s_setprio(0);

    // row max: pairwise tree
    float m8[8];
#pragma unroll
    for (int r = 0; r < 8; ++r)
      m8[r] = fmaxf(fmaxf(s0[r], s0[r + 8]), fmaxf(s1[r], s1[r + 8]));
    float m4a = fmaxf(m8[0], m8[4]), m4b = fmaxf(m8[1], m8[5]);
    float m4c = fmaxf(m8[2], m8[6]), m4d = fmaxf(m8[3], m8[7]);
    float mt = fmaxf(fmaxf(m4a, m4b), fmaxf(m4c, m4d));
    mt = fmaxf(mt, __shfl_xor(mt, 32));

    if (__any(mt > mr + 11.5415f)) {      // defer-max (T13), threshold in log2 units
      float mn = fmaxf(mr, mt);
      float sc = __builtin_exp2f(mr - mn);
      lr *= sc;
#pragma unroll
      for (int r = 0; r < 16; ++r) {
        float scr = __shfl(sc, CROW0[r] + 4 * hi);
        o0[r] *= scr; o1[r] *= scr;
      }
      mr = mn;
    }
#pragma unroll
    for (int r = 0; r < 16; ++r) {
      s0[r] = __builtin_exp2f(s0[r] - mr);
      s1[r] = __builtin_exp2f(s1[r] - mr);
    }
    // row sum: pairwise tree
    float a8[8];
#pragma unroll
    for (int r = 0; r < 8; ++r)
      a8[r] = (s0[r] + s0[r + 8]) + (s1[r] + s1[r + 8]);
    float a4a = a8[0] + a8[4], a4b = a8[1] + a8[5], a4c = a8[2] + a8[6], a4d = a8[3] + a8[7];
    float sum = (a4a + a4b) + (a4c + a4d);
    sum += __shfl_xor(sum, 32);
    lr += sum;

    // P (f32, S^T layout) -> PV A-fragments via cvt_pk + partner exchange
    bf8 pa[4];
#pragma unroll
    for (int t = 0; t < 2; ++t) {
      uint32_t wv[4][2];
#pragma unroll
      for (int g = 0; g < 4; ++g) {
        const float* sp = (t == 0) ? (const float*)&s0 : (const float*)&s1;
        wv[g][0] = cvtpk(sp[g * 4 + 0], sp[g * 4 + 1]);
        wv[g][1] = cvtpk(sp[g * 4 + 2], sp[g * 4 + 3]);
      }
#pragma unroll
      for (int pr = 0; pr < 2; ++pr) {
        uint32_t x0 = hi ? wv[2 * pr][0] : wv[2 * pr + 1][0];
        uint32_t x1 = hi ? wv[2 * pr][1] : wv[2 * pr + 1][1];
        uint32_t r0 = (uint32_t)__shfl_xor((int)x0, 32);
        uint32_t r1 = (uint32_t)__shfl_xor((int)x1, 32);
        uint4 pw;
        pw.x = hi ? r0 : wv[2 * pr][0];
        pw.y = hi ? r1 : wv[2 * pr][1];
        pw.z = hi ? wv[2 * pr + 1][0] : r0;
        pw.w = hi ? wv[2 * pr + 1][1] : r1;
        pa[t * 2 + pr] = __builtin_bit_cast(bf8, pw);
      }
    }

    // PV: O[q][d] += P[q][kv] V[kv][d]; V^T tile rows = d
    const ushort* Vb = &Vs[bi][0];
    __builtin_amdgcn_s_setprio(1);
#pragma unroll
    for (int ks = 0; ks < 4; ++ks) {
      int sl0 = ((ks * 2 + hi) ^ (l31 & 7)) * 8;
      bf8 v0 = *(const bf8*)(Vb + l31 * 64 + sl0);
      bf8 v1 = *(const bf8*)(Vb + (32 + l31) * 64 + sl0);
      o0 = __builtin_amdgcn_mfma_f32_32x32x16_bf16(pa[ks], v0, o0, 0, 0, 0);
      o1 = __builtin_amdgcn_mfma_f32_32x32x16_bf16(pa[ks], v1, o1, 0, 0, 0);
    }
    __builtin_amdgcn_s_setprio(0);
  };

  ushort4 biasA[8], biasB[8];
  STAGE(0, 0);  BLOAD(biasA, 0);
  STAGE(1, 64); BLOAD(biasB, 64);

#pragma unroll 1
  for (int t = 0; t < 32; t += 2) {
    asm volatile("s_waitcnt vmcnt(16)" ::: "memory");   // stage(t)+bias(t) drained
    __builtin_amdgcn_s_barrier();
    __builtin_amdgcn_sched_barrier(0);
    TILE(0, biasA);
    __builtin_amdgcn_s_barrier();                       // both warps done reading buf0
    __builtin_amdgcn_sched_barrier(0);
    if (t + 2 < 32) { STAGE(0, (t + 2) * 64); BLOAD(biasA, (t + 2) * 64); }

    if (t + 2 < 32) asm volatile("s_waitcnt vmcnt(16)" ::: "memory");
    else            asm volatile("s_waitcnt vmcnt(0)" ::: "memory");
    __builtin_amdgcn_s_barrier();
    __builtin_amdgcn_sched_barrier(0);
    TILE(1, biasB);
    __builtin_amdgcn_s_barrier();
    __builtin_amdgcn_sched_barrier(0);
    if (t + 3 < 32) { STAGE(1, (t + 3) * 64); BLOAD(biasB, (t + 3) * 64); }
  }

  // epilogue: O / l  (broadcast per-q inverse into the C/D row layout)
  float inv = 1.0f / lr;
#pragma unroll
  for (int r = 0; r < 16; ++r) {
    float ivr = __shfl(inv, CROW0[r] + 4 * hi);
    int q = q0 + w * 32 + CROW0[r] + 4 * hi;
    size_t base = ((size_t)b * S_N + q) * D_N + h * 64 + l31;
    AO[base]      = f2b(o0[r] * ivr);
    AO[base + 32] = f2b(o1[r] * ivr);
  }
}

extern "C" void kernel_launch(void* const* d_in, const int* in_sizes, int n_in,
                              void* d_out, int out_size, void* d_ws, size_t ws_size,
                              hipStream_t stream) {
  (void)in_sizes; (void)n_in; (void)out_size; (void)ws_size;
  const float* query = (const float*)d_in[0];
  const float* key_  = (const float*)d_in[1];
  const float* value = (const float*)d_in[2];
  const int* fid  = (const int*)d_in[3];
  const int* eid  = (const int*)d_in[4];
  const int* tmid = (const int*)d_in[5];
  const int* ttid = (const int*)d_in[6];
  const int* edid = (const int*)d_in[7];
  const int* rlid = (const int*)d_in[8];
  const float* Wq = (const float*)d_in[9];  const float* bq = (const float*)d_in[10];
  const float* Wk = (const float*)d_in[11]; const float* bk = (const float*)d_in[12];
  const float* Wv = (const float*)d_in[13]; const float* bv = (const float*)d_in[14];
  const float* Wo = (const float*)d_in[15]; const float* bo = (const float*)d_in[16];

  char* ws = (char*)d_ws;
  const size_t MB = 1024 * 1024;
  // Projection phase: Xq 0-8, Xk 8-16, Xv 16-24, Wqb 24-26, Wkb 26-28, Wvb 28-30 (MB).
  // After gemm_qkv those are dead; BM fp16 (16.8MB) overwrites [0,17).
  ushort* Xq  = (ushort*)(ws);
  ushort* Xk  = (ushort*)(ws + 8 * MB);
  ushort* Xv  = (ushort*)(ws + 16 * MB);
  ushort* Wqb = (ushort*)(ws + 24 * MB);
  ushort* Wkb = (ushort*)(ws + 26 * MB);
  ushort* Wvb = (ushort*)(ws + 28 * MB);
  ushort* BMh = (ushort*)(ws);                      // fp16 bias [B,S,S], log2-scaled
  ushort* Qws = (ushort*)(ws + 30 * MB);
  ushort* Kws = (ushort*)(ws + 38 * MB);
  ushort* VTw = (ushort*)(ws + 46 * MB);
  ushort* AOw = (ushort*)(ws + 54 * MB);
  ushort* Wob = (ushort*)(ws + 62 * MB);
  uint32_t* codes = (uint32_t*)(ws + 64 * MB);
  // total ws use: 64MB + 16KB

  const int MK = B_N * S_N * D_N;
  const int WK = D_N * D_N;
  cvt3_kernel<<<dim3(MK / 1024, 3), 256, 0, stream>>>(query, key_, value, Xq, Xk, Xv);
  cvt4_kernel<<<dim3(WK / 1024, 4), 256, 0, stream>>>(Wq, Wk, Wv, Wo, Wqb, Wkb, Wvb, Wob);
  pack_codes_kernel<<<(B_N * S_N) / 256, 256, 0, stream>>>(fid, eid, tmid, ttid, edid, rlid, codes, B_N * S_N);

  gemm_qkv<<<dim3(D_N / 128, (B_N * S_N) / 128, 3), 256, 0, stream>>>(
      Xq, Xk, Xv, Wqb, Wkb, Wvb, bq, bk, bv, Qws, Kws, VTw);
  // bias matrix overwrites Xq/Xk/start-of-Xv region (dead after gemm_qkv)
  bias_build<<<(B_N * S_N * S_N / 8) / 256, 256, 0, stream>>>(codes, BMh);
  attn_kernel<<<dim3(S_N / 64, B_N * H_N), 128, 0, stream>>>(Qws, Kws, VTw, BMh, AOw);
  gemm_o<<<dim3(D_N / 128, (B_N * S_N) / 128), 256, 0, stream>>>(AOw, Wob, bo, (float*)d_out);
}